// Round 6
// baseline (316.487 us; speedup 1.0000x reference)
//
#include <hip/hip_runtime.h>
#include <math.h>

#define NN 50000
#define EE 800000
#define ET (EE + NN)      // edges + self loops
#define F_IN 128
#define HEADS 8
#define HID 16
#define C1 (HEADS * HID)  // 128
#define CLASSES 40
#define NEG_SLOPE 0.2f

typedef __attribute__((ext_vector_type(8))) short bf16x8;
typedef __attribute__((ext_vector_type(4))) float f32x4;

__device__ __forceinline__ unsigned short f2bf(float f) {
    unsigned u = __float_as_uint(f);
    unsigned r = (u + 0x7fffu + ((u >> 16) & 1u)) >> 16;  // round-to-nearest-even
    return (unsigned short)r;
}
__device__ __forceinline__ float lrelu(float a) {
    return (a > 0.f) ? a : NEG_SLOPE * a;
}

// ---------------- GEMM1 (MFMA bf16): h1b = bf16(x @ W1) ----------------
__global__ void gemm1_kernel(const float* __restrict__ x, const float* __restrict__ W1,
                             unsigned short* __restrict__ h1b) {
    const int tid = threadIdx.x;
    const int w = tid >> 6, lane = tid & 63;
    const int q = lane >> 4, c = lane & 15;

    bf16x8 bfrag[2][4];
    #pragma unroll
    for (int nt = 0; nt < 2; ++nt) {
        const int col = w * 32 + nt * 16 + c;
        #pragma unroll
        for (int kc = 0; kc < 4; ++kc) {
            const int k0 = kc * 32 + q * 8;
            bf16x8 bb;
            #pragma unroll
            for (int j = 0; j < 8; ++j)
                bb[j] = (short)f2bf(W1[(size_t)(k0 + j) * C1 + col]);
            bfrag[nt][kc] = bb;
        }
    }

    #pragma unroll
    for (int mt = 0; mt < 2; ++mt) {
        const int m0 = (blockIdx.x * 2 + mt) * 16;
        if (m0 >= NN) break;
        int row = m0 + c;
        if (row > NN - 1) row = NN - 1;
        bf16x8 afrag[4];
        #pragma unroll
        for (int kc = 0; kc < 4; ++kc) {
            const float* xp = x + (size_t)row * F_IN + kc * 32 + q * 8;
            float4 p0 = *(const float4*)xp;
            float4 p1 = *(const float4*)(xp + 4);
            bf16x8 aa;
            aa[0] = (short)f2bf(p0.x); aa[1] = (short)f2bf(p0.y);
            aa[2] = (short)f2bf(p0.z); aa[3] = (short)f2bf(p0.w);
            aa[4] = (short)f2bf(p1.x); aa[5] = (short)f2bf(p1.y);
            aa[6] = (short)f2bf(p1.z); aa[7] = (short)f2bf(p1.w);
            afrag[kc] = aa;
        }
        f32x4 acc0 = {0.f, 0.f, 0.f, 0.f};
        f32x4 acc1 = {0.f, 0.f, 0.f, 0.f};
        #pragma unroll
        for (int kc = 0; kc < 4; ++kc) {
            acc0 = __builtin_amdgcn_mfma_f32_16x16x32_bf16(afrag[kc], bfrag[0][kc], acc0, 0, 0, 0);
            acc1 = __builtin_amdgcn_mfma_f32_16x16x32_bf16(afrag[kc], bfrag[1][kc], acc1, 0, 0, 0);
        }
        #pragma unroll
        for (int r = 0; r < 4; ++r) {
            const int ro = m0 + q * 4 + r;
            if (ro < NN) {
                h1b[(size_t)ro * C1 + w * 32 + c]      = f2bf(acc0[r]);
                h1b[(size_t)ro * C1 + w * 32 + 16 + c] = f2bf(acc1[r]);
            }
        }
    }
}

// ---------------- elogit1 ----------------
__global__ void elogit1_kernel(const unsigned short* __restrict__ h1b,
                               const float* __restrict__ a_src, const float* __restrict__ a_dst,
                               float* __restrict__ e_src, float* __restrict__ e_dst) {
    int t = blockIdx.x * blockDim.x + threadIdx.x;
    if (t >= NN * HEADS) return;
    int n = t >> 3, hd = t & 7;
    const uint4* hp = (const uint4*)(h1b + (size_t)n * C1 + hd * HID);
    uint4 g0 = hp[0], g1 = hp[1];
    const float* as = a_src + hd * HID;
    const float* ad = a_dst + hd * HID;
    unsigned gs[8] = {g0.x, g0.y, g0.z, g0.w, g1.x, g1.y, g1.z, g1.w};
    float ss = 0.f, sd = 0.f;
    #pragma unroll
    for (int j = 0; j < 8; ++j) {
        float lo = __uint_as_float(gs[j] << 16);
        float hi = __uint_as_float(gs[j] & 0xffff0000u);
        ss += lo * as[2 * j] + hi * as[2 * j + 1];
        sd += lo * ad[2 * j] + hi * ad[2 * j + 1];
    }
    e_src[t] = ss;
    e_dst[t] = sd;
}

// ---------------- CSR build (real edges only; self-loops handled in scan3) ----------------
// 4 edges per thread, int4 loads.
__global__ void count_kernel(const int* __restrict__ ei, int* __restrict__ deg) {
    int base = (blockIdx.x * blockDim.x + threadIdx.x) * 4;
    if (base >= EE) return;
    int4 d4 = *(const int4*)(ei + EE + base);
    atomicAdd(&deg[d4.x], 1);
    atomicAdd(&deg[d4.y], 1);
    atomicAdd(&deg[d4.z], 1);
    atomicAdd(&deg[d4.w], 1);
}

// exclusive scan over (deg[i] + 1)  [+1 = self-loop]
__global__ void scan1_kernel(const int* __restrict__ deg, int* __restrict__ rowptr,
                             int* __restrict__ bsum) {
    __shared__ int sh[256];
    const int tid = threadIdx.x;
    const int base = blockIdx.x * 1024 + tid * 4;
    int v[4], s[4];
    #pragma unroll
    for (int j = 0; j < 4; ++j) v[j] = (base + j < NN) ? (deg[base + j] + 1) : 0;
    s[0] = v[0]; s[1] = s[0] + v[1]; s[2] = s[1] + v[2]; s[3] = s[2] + v[3];
    int T = s[3];
    sh[tid] = T;
    __syncthreads();
    for (int off = 1; off < 256; off <<= 1) {
        int xv = (tid >= off) ? sh[tid - off] : 0;
        __syncthreads();
        sh[tid] += xv;
        __syncthreads();
    }
    int excl = sh[tid] - T;
    #pragma unroll
    for (int j = 0; j < 4; ++j)
        if (base + j < NN) rowptr[base + j] = excl + s[j] - v[j];
    if (tid == 255) bsum[blockIdx.x] = sh[255];
}

__global__ void scan2_kernel(int* __restrict__ bsum, int nchunks) {
    __shared__ int sh[64];
    const int tid = threadIdx.x;
    int v = (tid < nchunks) ? bsum[tid] : 0;
    sh[tid] = v;
    __syncthreads();
    for (int off = 1; off < 64; off <<= 1) {
        int xv = (tid >= off) ? sh[tid - off] : 0;
        __syncthreads();
        sh[tid] += xv;
        __syncthreads();
    }
    if (tid < nchunks) bsum[tid] = sh[tid] - v;  // exclusive
}

// finalize rowptr; place self-loop at slot rowptr[i]; cursor starts past it; deg -> total cnt
__global__ void scan3_kernel(int* __restrict__ rowptr, const int* __restrict__ bsum,
                             int* __restrict__ cursor, int* __restrict__ csr,
                             int* __restrict__ deg) {
    int i = blockIdx.x * blockDim.x + threadIdx.x;
    if (i >= NN) return;
    int rp = rowptr[i] + bsum[i >> 10];
    rowptr[i] = rp;
    cursor[i] = rp + 1;
    __builtin_nontemporal_store(i, &csr[rp]);  // self-loop first
    deg[i] += 1;                                // total incoming count incl. self-loop
}

// scatter real edges: 4 per thread, int4 loads, NT stores
__global__ void fill_kernel(const int* __restrict__ ei, int* __restrict__ cursor,
                            int* __restrict__ csr) {
    int base = (blockIdx.x * blockDim.x + threadIdx.x) * 4;
    if (base >= EE) return;
    int4 s4 = *(const int4*)(ei + base);
    int4 d4 = *(const int4*)(ei + EE + base);
    int p0 = atomicAdd(&cursor[d4.x], 1);
    int p1 = atomicAdd(&cursor[d4.y], 1);
    int p2 = atomicAdd(&cursor[d4.z], 1);
    int p3 = atomicAdd(&cursor[d4.w], 1);
    __builtin_nontemporal_store(s4.x, &csr[p0]);
    __builtin_nontemporal_store(s4.y, &csr[p1]);
    __builtin_nontemporal_store(s4.z, &csr[p2]);
    __builtin_nontemporal_store(s4.w, &csr[p3]);
}

// ---------------- layer-1 aggregation: wave per node, 4x edge unroll ----------------
__global__ void agg1_kernel(const unsigned short* __restrict__ h1b,
                            const float* __restrict__ e_src, const float* __restrict__ e_dst,
                            const int* __restrict__ rowptr, const int* __restrict__ deg,
                            const int* __restrict__ csr,
                            const float* __restrict__ b1, float* __restrict__ hmid) {
    const int d = blockIdx.x * 4 + (threadIdx.x >> 6);
    const int lane = threadIdx.x & 63;
    const int hd = lane >> 3;
    const float ed = e_dst[(size_t)d * HEADS + hd];
    const int start = rowptr[d];
    const int cnt = deg[d];

    float denom = 0.f, acc0 = 0.f, acc1 = 0.f;
    int i = 0;
    for (; i + 4 <= cnt; i += 4) {
        int s0 = csr[start + i];
        int s1 = csr[start + i + 1];
        int s2 = csr[start + i + 2];
        int s3 = csr[start + i + 3];
        float es0 = e_src[(size_t)s0 * HEADS + hd];
        float es1 = e_src[(size_t)s1 * HEADS + hd];
        float es2 = e_src[(size_t)s2 * HEADS + hd];
        float es3 = e_src[(size_t)s3 * HEADS + hd];
        unsigned g0 = *(const unsigned*)(h1b + (size_t)s0 * C1 + 2 * lane);
        unsigned g1 = *(const unsigned*)(h1b + (size_t)s1 * C1 + 2 * lane);
        unsigned g2 = *(const unsigned*)(h1b + (size_t)s2 * C1 + 2 * lane);
        unsigned g3 = *(const unsigned*)(h1b + (size_t)s3 * C1 + 2 * lane);
        float w0 = __expf(lrelu(es0 + ed));
        float w1 = __expf(lrelu(es1 + ed));
        float w2 = __expf(lrelu(es2 + ed));
        float w3 = __expf(lrelu(es3 + ed));
        denom += (w0 + w1) + (w2 + w3);
        acc0 += w0 * __uint_as_float(g0 << 16) + w1 * __uint_as_float(g1 << 16)
              + w2 * __uint_as_float(g2 << 16) + w3 * __uint_as_float(g3 << 16);
        acc1 += w0 * __uint_as_float(g0 & 0xffff0000u) + w1 * __uint_as_float(g1 & 0xffff0000u)
              + w2 * __uint_as_float(g2 & 0xffff0000u) + w3 * __uint_as_float(g3 & 0xffff0000u);
    }
    for (; i < cnt; ++i) {
        int s0 = csr[start + i];
        float es0 = e_src[(size_t)s0 * HEADS + hd];
        unsigned g0 = *(const unsigned*)(h1b + (size_t)s0 * C1 + 2 * lane);
        float w0 = __expf(lrelu(es0 + ed));
        denom += w0;
        acc0 += w0 * __uint_as_float(g0 << 16);
        acc1 += w0 * __uint_as_float(g0 & 0xffff0000u);
    }
    float inv = 1.f / (denom + 1e-16f);
    float o0 = acc0 * inv + b1[2 * lane];
    float o1 = acc1 * inv + b1[2 * lane + 1];
    o0 = (o0 > 0.f) ? o0 : expm1f(o0);
    o1 = (o1 > 0.f) ? o1 : expm1f(o1);
    *(float2*)(hmid + (size_t)d * C1 + 2 * lane) = make_float2(o0, o1);
}

// ---------------- GEMM2 (MFMA bf16): h2b = bf16(hmid @ W2) ----------------
__global__ void gemm2_kernel(const float* __restrict__ hmid, const float* __restrict__ W2,
                             unsigned short* __restrict__ h2b) {
    const int tid = threadIdx.x;
    const int w = tid >> 6, lane = tid & 63;
    const int q = lane >> 4, c = lane & 15;

    bf16x8 bfrag[3][4];
    #pragma unroll
    for (int nt = 0; nt < 3; ++nt) {
        const int col = nt * 16 + c;
        const bool cv = col < CLASSES;
        #pragma unroll
        for (int kc = 0; kc < 4; ++kc) {
            const int k0 = kc * 32 + q * 8;
            bf16x8 bb;
            #pragma unroll
            for (int j = 0; j < 8; ++j)
                bb[j] = cv ? (short)f2bf(W2[(size_t)(k0 + j) * CLASSES + col]) : (short)0;
            bfrag[nt][kc] = bb;
        }
    }

    const int m0 = (blockIdx.x * 4 + w) * 16;
    if (m0 >= NN) return;
    int row = m0 + c;
    if (row > NN - 1) row = NN - 1;
    bf16x8 afrag[4];
    #pragma unroll
    for (int kc = 0; kc < 4; ++kc) {
        const float* xp = hmid + (size_t)row * F_IN + kc * 32 + q * 8;
        float4 p0 = *(const float4*)xp;
        float4 p1 = *(const float4*)(xp + 4);
        bf16x8 aa;
        aa[0] = (short)f2bf(p0.x); aa[1] = (short)f2bf(p0.y);
        aa[2] = (short)f2bf(p0.z); aa[3] = (short)f2bf(p0.w);
        aa[4] = (short)f2bf(p1.x); aa[5] = (short)f2bf(p1.y);
        aa[6] = (short)f2bf(p1.z); aa[7] = (short)f2bf(p1.w);
        afrag[kc] = aa;
    }
    f32x4 acc[3] = {{0.f,0.f,0.f,0.f},{0.f,0.f,0.f,0.f},{0.f,0.f,0.f,0.f}};
    #pragma unroll
    for (int kc = 0; kc < 4; ++kc) {
        acc[0] = __builtin_amdgcn_mfma_f32_16x16x32_bf16(afrag[kc], bfrag[0][kc], acc[0], 0, 0, 0);
        acc[1] = __builtin_amdgcn_mfma_f32_16x16x32_bf16(afrag[kc], bfrag[1][kc], acc[1], 0, 0, 0);
        acc[2] = __builtin_amdgcn_mfma_f32_16x16x32_bf16(afrag[kc], bfrag[2][kc], acc[2], 0, 0, 0);
    }
    #pragma unroll
    for (int nt = 0; nt < 3; ++nt) {
        const int col = nt * 16 + c;
        if (col >= CLASSES) continue;
        #pragma unroll
        for (int r = 0; r < 4; ++r) {
            const int ro = m0 + q * 4 + r;
            if (ro < NN) h2b[(size_t)ro * CLASSES + col] = f2bf(acc[nt][r]);
        }
    }
}

// ---------------- elogit2 ----------------
__global__ void elogit2_kernel(const unsigned short* __restrict__ h2b,
                               const float* __restrict__ a_src, const float* __restrict__ a_dst,
                               float* __restrict__ e_src, float* __restrict__ e_dst) {
    int n = blockIdx.x * blockDim.x + threadIdx.x;
    if (n >= NN) return;
    const unsigned* hp = (const unsigned*)(h2b + (size_t)n * CLASSES);
    float ss = 0.f, sd = 0.f;
    #pragma unroll
    for (int j = 0; j < CLASSES / 2; ++j) {
        unsigned g = hp[j];
        float lo = __uint_as_float(g << 16);
        float hi = __uint_as_float(g & 0xffff0000u);
        ss += lo * a_src[2 * j] + hi * a_src[2 * j + 1];
        sd += lo * a_dst[2 * j] + hi * a_dst[2 * j + 1];
    }
    e_src[n] = ss;
    e_dst[n] = sd;
}

// ---------------- layer-2 aggregation -> output ----------------
__global__ void agg2_kernel(const unsigned short* __restrict__ h2b,
                            const float* __restrict__ e_src, const float* __restrict__ e_dst,
                            const int* __restrict__ rowptr, const int* __restrict__ deg,
                            const int* __restrict__ csr,
                            const float* __restrict__ b2, float* __restrict__ out) {
    const int d = blockIdx.x * 4 + (threadIdx.x >> 6);
    const int lane = threadIdx.x & 63;
    const bool act = lane < CLASSES / 2;  // lanes 0..19 own cols 2l,2l+1
    const float ed = e_dst[d];
    const int start = rowptr[d];
    const int cnt = deg[d];

    float denom = 0.f, acc0 = 0.f, acc1 = 0.f;
    int i = 0;
    for (; i + 4 <= cnt; i += 4) {
        int s0 = csr[start + i];
        int s1 = csr[start + i + 1];
        int s2 = csr[start + i + 2];
        int s3 = csr[start + i + 3];
        float es0 = e_src[s0], es1 = e_src[s1], es2 = e_src[s2], es3 = e_src[s3];
        unsigned g0 = 0, g1 = 0, g2 = 0, g3 = 0;
        if (act) {
            g0 = *(const unsigned*)(h2b + (size_t)s0 * CLASSES + 2 * lane);
            g1 = *(const unsigned*)(h2b + (size_t)s1 * CLASSES + 2 * lane);
            g2 = *(const unsigned*)(h2b + (size_t)s2 * CLASSES + 2 * lane);
            g3 = *(const unsigned*)(h2b + (size_t)s3 * CLASSES + 2 * lane);
        }
        float w0 = __expf(lrelu(es0 + ed));
        float w1 = __expf(lrelu(es1 + ed));
        float w2 = __expf(lrelu(es2 + ed));
        float w3 = __expf(lrelu(es3 + ed));
        denom += (w0 + w1) + (w2 + w3);
        acc0 += w0 * __uint_as_float(g0 << 16) + w1 * __uint_as_float(g1 << 16)
              + w2 * __uint_as_float(g2 << 16) + w3 * __uint_as_float(g3 << 16);
        acc1 += w0 * __uint_as_float(g0 & 0xffff0000u) + w1 * __uint_as_float(g1 & 0xffff0000u)
              + w2 * __uint_as_float(g2 & 0xffff0000u) + w3 * __uint_as_float(g3 & 0xffff0000u);
    }
    for (; i < cnt; ++i) {
        int s0 = csr[start + i];
        float w0 = __expf(lrelu(e_src[s0] + ed));
        unsigned g0 = act ? *(const unsigned*)(h2b + (size_t)s0 * CLASSES + 2 * lane) : 0;
        denom += w0;
        acc0 += w0 * __uint_as_float(g0 << 16);
        acc1 += w0 * __uint_as_float(g0 & 0xffff0000u);
    }
    if (act) {
        float inv = 1.f / (denom + 1e-16f);
        out[(size_t)d * CLASSES + 2 * lane]     = acc0 * inv + b2[2 * lane];
        out[(size_t)d * CLASSES + 2 * lane + 1] = acc1 * inv + b2[2 * lane + 1];
    }
}

extern "C" void kernel_launch(void* const* d_in, const int* in_sizes, int n_in,
                              void* d_out, int out_size, void* d_ws, size_t ws_size,
                              hipStream_t stream) {
    const float* x      = (const float*)d_in[0];
    const int*   ei     = (const int*)d_in[1];
    const float* W1     = (const float*)d_in[2];
    const float* a_src1 = (const float*)d_in[3];
    const float* a_dst1 = (const float*)d_in[4];
    const float* b1     = (const float*)d_in[5];
    const float* W2     = (const float*)d_in[6];
    const float* a_src2 = (const float*)d_in[7];
    const float* a_dst2 = (const float*)d_in[8];
    const float* b2     = (const float*)d_in[9];
    float* out = (float*)d_out;

    char* ws = (char*)d_ws;
    size_t off = 0;
    auto alloc = [&](size_t bytes) { char* p = ws + off; off += (bytes + 255) & ~(size_t)255; return p; };
    unsigned short* h1b = (unsigned short*)alloc((size_t)NN * C1 * 2);
    unsigned short* h2b = (unsigned short*)alloc((size_t)NN * CLASSES * 2);
    float* hmid   = (float*)alloc((size_t)NN * C1 * 4);
    float* e_src1 = (float*)alloc((size_t)NN * HEADS * 4);
    float* e_dst1 = (float*)alloc((size_t)NN * HEADS * 4);
    float* e_src2 = (float*)alloc((size_t)NN * 4);
    float* e_dst2 = (float*)alloc((size_t)NN * 4);
    int*   deg    = (int*)alloc((size_t)NN * 4);
    int*   rowptr = (int*)alloc((size_t)NN * 4);
    int*   cursor = (int*)alloc((size_t)NN * 4);
    int*   csr    = (int*)alloc((size_t)ET * 4);
    int*   bsum   = (int*)alloc(256 * 4);

    hipMemsetAsync(deg, 0, (size_t)NN * 4, stream);

    gemm1_kernel<<<(NN + 31) / 32, 256, 0, stream>>>(x, W1, h1b);
    elogit1_kernel<<<(NN * HEADS + 255) / 256, 256, 0, stream>>>(h1b, a_src1, a_dst1, e_src1, e_dst1);

    count_kernel<<<(EE / 4 + 255) / 256, 256, 0, stream>>>(ei, deg);
    const int nchunks = (NN + 1023) / 1024;  // 49
    scan1_kernel<<<nchunks, 256, 0, stream>>>(deg, rowptr, bsum);
    scan2_kernel<<<1, 64, 0, stream>>>(bsum, nchunks);
    scan3_kernel<<<(NN + 255) / 256, 256, 0, stream>>>(rowptr, bsum, cursor, csr, deg);
    fill_kernel<<<(EE / 4 + 255) / 256, 256, 0, stream>>>(ei, cursor, csr);

    agg1_kernel<<<NN / 4, 256, 0, stream>>>(h1b, e_src1, e_dst1, rowptr, deg, csr, b1, hmid);

    gemm2_kernel<<<(NN + 63) / 64, 256, 0, stream>>>(hmid, W2, h2b);
    elogit2_kernel<<<(NN + 255) / 256, 256, 0, stream>>>(h2b, a_src2, a_dst2, e_src2, e_dst2);

    agg2_kernel<<<NN / 4, 256, 0, stream>>>(h2b, e_src2, e_dst2, rowptr, deg, csr, b2, out);
}

// Round 7
// 302.399 us; speedup vs baseline: 1.0466x; 1.0466x over previous
//
#include <hip/hip_runtime.h>
#include <math.h>

#define NN 50000
#define EE 800000
#define ET (EE + NN)      // edges + self loops
#define F_IN 128
#define HEADS 8
#define HID 16
#define C1 (HEADS * HID)  // 128
#define CLASSES 40
#define NEG_SLOPE 0.2f

typedef __attribute__((ext_vector_type(8))) short bf16x8;
typedef __attribute__((ext_vector_type(4))) float f32x4;

__device__ __forceinline__ unsigned short f2bf(float f) {
    unsigned u = __float_as_uint(f);
    unsigned r = (u + 0x7fffu + ((u >> 16) & 1u)) >> 16;  // round-to-nearest-even
    return (unsigned short)r;
}
__device__ __forceinline__ float lrelu(float a) {
    return (a > 0.f) ? a : NEG_SLOPE * a;
}

// ---------------- GEMM1 (MFMA bf16): h1b = bf16(x @ W1) ----------------
__global__ void gemm1_kernel(const float* __restrict__ x, const float* __restrict__ W1,
                             unsigned short* __restrict__ h1b) {
    const int tid = threadIdx.x;
    const int w = tid >> 6, lane = tid & 63;
    const int q = lane >> 4, c = lane & 15;

    bf16x8 bfrag[2][4];
    #pragma unroll
    for (int nt = 0; nt < 2; ++nt) {
        const int col = w * 32 + nt * 16 + c;
        #pragma unroll
        for (int kc = 0; kc < 4; ++kc) {
            const int k0 = kc * 32 + q * 8;
            bf16x8 bb;
            #pragma unroll
            for (int j = 0; j < 8; ++j)
                bb[j] = (short)f2bf(W1[(size_t)(k0 + j) * C1 + col]);
            bfrag[nt][kc] = bb;
        }
    }

    #pragma unroll
    for (int mt = 0; mt < 2; ++mt) {
        const int m0 = (blockIdx.x * 2 + mt) * 16;
        if (m0 >= NN) break;
        int row = m0 + c;
        if (row > NN - 1) row = NN - 1;
        bf16x8 afrag[4];
        #pragma unroll
        for (int kc = 0; kc < 4; ++kc) {
            const float* xp = x + (size_t)row * F_IN + kc * 32 + q * 8;
            float4 p0 = *(const float4*)xp;
            float4 p1 = *(const float4*)(xp + 4);
            bf16x8 aa;
            aa[0] = (short)f2bf(p0.x); aa[1] = (short)f2bf(p0.y);
            aa[2] = (short)f2bf(p0.z); aa[3] = (short)f2bf(p0.w);
            aa[4] = (short)f2bf(p1.x); aa[5] = (short)f2bf(p1.y);
            aa[6] = (short)f2bf(p1.z); aa[7] = (short)f2bf(p1.w);
            afrag[kc] = aa;
        }
        f32x4 acc0 = {0.f, 0.f, 0.f, 0.f};
        f32x4 acc1 = {0.f, 0.f, 0.f, 0.f};
        #pragma unroll
        for (int kc = 0; kc < 4; ++kc) {
            acc0 = __builtin_amdgcn_mfma_f32_16x16x32_bf16(afrag[kc], bfrag[0][kc], acc0, 0, 0, 0);
            acc1 = __builtin_amdgcn_mfma_f32_16x16x32_bf16(afrag[kc], bfrag[1][kc], acc1, 0, 0, 0);
        }
        #pragma unroll
        for (int r = 0; r < 4; ++r) {
            const int ro = m0 + q * 4 + r;
            if (ro < NN) {
                h1b[(size_t)ro * C1 + w * 32 + c]      = f2bf(acc0[r]);
                h1b[(size_t)ro * C1 + w * 32 + 16 + c] = f2bf(acc1[r]);
            }
        }
    }
}

// ---------------- elogit1 ----------------
__global__ void elogit1_kernel(const unsigned short* __restrict__ h1b,
                               const float* __restrict__ a_src, const float* __restrict__ a_dst,
                               float* __restrict__ e_src, float* __restrict__ e_dst) {
    int t = blockIdx.x * blockDim.x + threadIdx.x;
    if (t >= NN * HEADS) return;
    int n = t >> 3, hd = t & 7;
    const uint4* hp = (const uint4*)(h1b + (size_t)n * C1 + hd * HID);
    uint4 g0 = hp[0], g1 = hp[1];
    const float* as = a_src + hd * HID;
    const float* ad = a_dst + hd * HID;
    unsigned gs[8] = {g0.x, g0.y, g0.z, g0.w, g1.x, g1.y, g1.z, g1.w};
    float ss = 0.f, sd = 0.f;
    #pragma unroll
    for (int j = 0; j < 8; ++j) {
        float lo = __uint_as_float(gs[j] << 16);
        float hi = __uint_as_float(gs[j] & 0xffff0000u);
        ss += lo * as[2 * j] + hi * as[2 * j + 1];
        sd += lo * ad[2 * j] + hi * ad[2 * j + 1];
    }
    e_src[t] = ss;
    e_dst[t] = sd;
}

// ---------------- CSR build (real edges only; self-loops handled in scan3) ----------------
__global__ void count_kernel(const int* __restrict__ ei, int* __restrict__ deg) {
    int base = (blockIdx.x * blockDim.x + threadIdx.x) * 4;
    if (base >= EE) return;
    int4 d4 = *(const int4*)(ei + EE + base);
    atomicAdd(&deg[d4.x], 1);
    atomicAdd(&deg[d4.y], 1);
    atomicAdd(&deg[d4.z], 1);
    atomicAdd(&deg[d4.w], 1);
}

// exclusive scan over (deg[i] + 1)  [+1 = self-loop]
__global__ void scan1_kernel(const int* __restrict__ deg, int* __restrict__ rowptr,
                             int* __restrict__ bsum) {
    __shared__ int sh[256];
    const int tid = threadIdx.x;
    const int base = blockIdx.x * 1024 + tid * 4;
    int v[4], s[4];
    #pragma unroll
    for (int j = 0; j < 4; ++j) v[j] = (base + j < NN) ? (deg[base + j] + 1) : 0;
    s[0] = v[0]; s[1] = s[0] + v[1]; s[2] = s[1] + v[2]; s[3] = s[2] + v[3];
    int T = s[3];
    sh[tid] = T;
    __syncthreads();
    for (int off = 1; off < 256; off <<= 1) {
        int xv = (tid >= off) ? sh[tid - off] : 0;
        __syncthreads();
        sh[tid] += xv;
        __syncthreads();
    }
    int excl = sh[tid] - T;
    #pragma unroll
    for (int j = 0; j < 4; ++j)
        if (base + j < NN) rowptr[base + j] = excl + s[j] - v[j];
    if (tid == 255) bsum[blockIdx.x] = sh[255];
}

__global__ void scan2_kernel(int* __restrict__ bsum, int nchunks) {
    __shared__ int sh[64];
    const int tid = threadIdx.x;
    int v = (tid < nchunks) ? bsum[tid] : 0;
    sh[tid] = v;
    __syncthreads();
    for (int off = 1; off < 64; off <<= 1) {
        int xv = (tid >= off) ? sh[tid - off] : 0;
        __syncthreads();
        sh[tid] += xv;
        __syncthreads();
    }
    if (tid < nchunks) bsum[tid] = sh[tid] - v;  // exclusive
}

// finalize rowptr; self-loop at slot rowptr[i]; cursor starts past it; deg -> total cnt
__global__ void scan3_kernel(int* __restrict__ rowptr, const int* __restrict__ bsum,
                             int* __restrict__ cursor, unsigned short* __restrict__ csr,
                             int* __restrict__ deg) {
    int i = blockIdx.x * blockDim.x + threadIdx.x;
    if (i >= NN) return;
    int rp = rowptr[i] + bsum[i >> 10];
    rowptr[i] = rp;
    cursor[i] = rp + 1;
    csr[rp] = (unsigned short)i;  // self-loop first
    deg[i] += 1;                  // total incoming count incl. self-loop
}

// scatter real edges: 4 per thread, int4 loads, ushort payloads (L2-merged stores)
__global__ void fill_kernel(const int* __restrict__ ei, int* __restrict__ cursor,
                            unsigned short* __restrict__ csr) {
    int base = (blockIdx.x * blockDim.x + threadIdx.x) * 4;
    if (base >= EE) return;
    int4 s4 = *(const int4*)(ei + base);
    int4 d4 = *(const int4*)(ei + EE + base);
    int p0 = atomicAdd(&cursor[d4.x], 1);
    int p1 = atomicAdd(&cursor[d4.y], 1);
    int p2 = atomicAdd(&cursor[d4.z], 1);
    int p3 = atomicAdd(&cursor[d4.w], 1);
    csr[p0] = (unsigned short)s4.x;
    csr[p1] = (unsigned short)s4.y;
    csr[p2] = (unsigned short)s4.z;
    csr[p3] = (unsigned short)s4.w;
}

// ---------------- layer-1 aggregation: wave per node, 4x edge unroll ----------------
__global__ void agg1_kernel(const unsigned short* __restrict__ h1b,
                            const float* __restrict__ e_src, const float* __restrict__ e_dst,
                            const int* __restrict__ rowptr, const int* __restrict__ deg,
                            const unsigned short* __restrict__ csr,
                            const float* __restrict__ b1, float* __restrict__ hmid) {
    const int d = blockIdx.x * 4 + (threadIdx.x >> 6);
    const int lane = threadIdx.x & 63;
    const int hd = lane >> 3;
    const float ed = e_dst[(size_t)d * HEADS + hd];
    const int start = rowptr[d];
    const int cnt = deg[d];

    float denom = 0.f, acc0 = 0.f, acc1 = 0.f;
    int i = 0;
    for (; i + 4 <= cnt; i += 4) {
        int s0 = csr[start + i];
        int s1 = csr[start + i + 1];
        int s2 = csr[start + i + 2];
        int s3 = csr[start + i + 3];
        float es0 = e_src[(size_t)s0 * HEADS + hd];
        float es1 = e_src[(size_t)s1 * HEADS + hd];
        float es2 = e_src[(size_t)s2 * HEADS + hd];
        float es3 = e_src[(size_t)s3 * HEADS + hd];
        unsigned g0 = *(const unsigned*)(h1b + (size_t)s0 * C1 + 2 * lane);
        unsigned g1 = *(const unsigned*)(h1b + (size_t)s1 * C1 + 2 * lane);
        unsigned g2 = *(const unsigned*)(h1b + (size_t)s2 * C1 + 2 * lane);
        unsigned g3 = *(const unsigned*)(h1b + (size_t)s3 * C1 + 2 * lane);
        float w0 = __expf(lrelu(es0 + ed));
        float w1 = __expf(lrelu(es1 + ed));
        float w2 = __expf(lrelu(es2 + ed));
        float w3 = __expf(lrelu(es3 + ed));
        denom += (w0 + w1) + (w2 + w3);
        acc0 += w0 * __uint_as_float(g0 << 16) + w1 * __uint_as_float(g1 << 16)
              + w2 * __uint_as_float(g2 << 16) + w3 * __uint_as_float(g3 << 16);
        acc1 += w0 * __uint_as_float(g0 & 0xffff0000u) + w1 * __uint_as_float(g1 & 0xffff0000u)
              + w2 * __uint_as_float(g2 & 0xffff0000u) + w3 * __uint_as_float(g3 & 0xffff0000u);
    }
    for (; i < cnt; ++i) {
        int s0 = csr[start + i];
        float es0 = e_src[(size_t)s0 * HEADS + hd];
        unsigned g0 = *(const unsigned*)(h1b + (size_t)s0 * C1 + 2 * lane);
        float w0 = __expf(lrelu(es0 + ed));
        denom += w0;
        acc0 += w0 * __uint_as_float(g0 << 16);
        acc1 += w0 * __uint_as_float(g0 & 0xffff0000u);
    }
    float inv = 1.f / (denom + 1e-16f);
    float o0 = acc0 * inv + b1[2 * lane];
    float o1 = acc1 * inv + b1[2 * lane + 1];
    o0 = (o0 > 0.f) ? o0 : expm1f(o0);
    o1 = (o1 > 0.f) ? o1 : expm1f(o1);
    *(float2*)(hmid + (size_t)d * C1 + 2 * lane) = make_float2(o0, o1);
}

// ---------------- GEMM2 (MFMA bf16): h2b = bf16(hmid @ W2) ----------------
__global__ void gemm2_kernel(const float* __restrict__ hmid, const float* __restrict__ W2,
                             unsigned short* __restrict__ h2b) {
    const int tid = threadIdx.x;
    const int w = tid >> 6, lane = tid & 63;
    const int q = lane >> 4, c = lane & 15;

    bf16x8 bfrag[3][4];
    #pragma unroll
    for (int nt = 0; nt < 3; ++nt) {
        const int col = nt * 16 + c;
        const bool cv = col < CLASSES;
        #pragma unroll
        for (int kc = 0; kc < 4; ++kc) {
            const int k0 = kc * 32 + q * 8;
            bf16x8 bb;
            #pragma unroll
            for (int j = 0; j < 8; ++j)
                bb[j] = cv ? (short)f2bf(W2[(size_t)(k0 + j) * CLASSES + col]) : (short)0;
            bfrag[nt][kc] = bb;
        }
    }

    const int m0 = (blockIdx.x * 4 + w) * 16;
    if (m0 >= NN) return;
    int row = m0 + c;
    if (row > NN - 1) row = NN - 1;
    bf16x8 afrag[4];
    #pragma unroll
    for (int kc = 0; kc < 4; ++kc) {
        const float* xp = hmid + (size_t)row * F_IN + kc * 32 + q * 8;
        float4 p0 = *(const float4*)xp;
        float4 p1 = *(const float4*)(xp + 4);
        bf16x8 aa;
        aa[0] = (short)f2bf(p0.x); aa[1] = (short)f2bf(p0.y);
        aa[2] = (short)f2bf(p0.z); aa[3] = (short)f2bf(p0.w);
        aa[4] = (short)f2bf(p1.x); aa[5] = (short)f2bf(p1.y);
        aa[6] = (short)f2bf(p1.z); aa[7] = (short)f2bf(p1.w);
        afrag[kc] = aa;
    }
    f32x4 acc[3] = {{0.f,0.f,0.f,0.f},{0.f,0.f,0.f,0.f},{0.f,0.f,0.f,0.f}};
    #pragma unroll
    for (int kc = 0; kc < 4; ++kc) {
        acc[0] = __builtin_amdgcn_mfma_f32_16x16x32_bf16(afrag[kc], bfrag[0][kc], acc[0], 0, 0, 0);
        acc[1] = __builtin_amdgcn_mfma_f32_16x16x32_bf16(afrag[kc], bfrag[1][kc], acc[1], 0, 0, 0);
        acc[2] = __builtin_amdgcn_mfma_f32_16x16x32_bf16(afrag[kc], bfrag[2][kc], acc[2], 0, 0, 0);
    }
    #pragma unroll
    for (int nt = 0; nt < 3; ++nt) {
        const int col = nt * 16 + c;
        if (col >= CLASSES) continue;
        #pragma unroll
        for (int r = 0; r < 4; ++r) {
            const int ro = m0 + q * 4 + r;
            if (ro < NN) h2b[(size_t)ro * CLASSES + col] = f2bf(acc[nt][r]);
        }
    }
}

// ---------------- elogit2 ----------------
__global__ void elogit2_kernel(const unsigned short* __restrict__ h2b,
                               const float* __restrict__ a_src, const float* __restrict__ a_dst,
                               float* __restrict__ e_src, float* __restrict__ e_dst) {
    int n = blockIdx.x * blockDim.x + threadIdx.x;
    if (n >= NN) return;
    const unsigned* hp = (const unsigned*)(h2b + (size_t)n * CLASSES);
    float ss = 0.f, sd = 0.f;
    #pragma unroll
    for (int j = 0; j < CLASSES / 2; ++j) {
        unsigned g = hp[j];
        float lo = __uint_as_float(g << 16);
        float hi = __uint_as_float(g & 0xffff0000u);
        ss += lo * a_src[2 * j] + hi * a_src[2 * j + 1];
        sd += lo * a_dst[2 * j] + hi * a_dst[2 * j + 1];
    }
    e_src[n] = ss;
    e_dst[n] = sd;
}

// ---------------- layer-2 aggregation -> output ----------------
__global__ void agg2_kernel(const unsigned short* __restrict__ h2b,
                            const float* __restrict__ e_src, const float* __restrict__ e_dst,
                            const int* __restrict__ rowptr, const int* __restrict__ deg,
                            const unsigned short* __restrict__ csr,
                            const float* __restrict__ b2, float* __restrict__ out) {
    const int d = blockIdx.x * 4 + (threadIdx.x >> 6);
    const int lane = threadIdx.x & 63;
    const bool act = lane < CLASSES / 2;  // lanes 0..19 own cols 2l,2l+1
    const float ed = e_dst[d];
    const int start = rowptr[d];
    const int cnt = deg[d];

    float denom = 0.f, acc0 = 0.f, acc1 = 0.f;
    int i = 0;
    for (; i + 4 <= cnt; i += 4) {
        int s0 = csr[start + i];
        int s1 = csr[start + i + 1];
        int s2 = csr[start + i + 2];
        int s3 = csr[start + i + 3];
        float es0 = e_src[s0], es1 = e_src[s1], es2 = e_src[s2], es3 = e_src[s3];
        unsigned g0 = 0, g1 = 0, g2 = 0, g3 = 0;
        if (act) {
            g0 = *(const unsigned*)(h2b + (size_t)s0 * CLASSES + 2 * lane);
            g1 = *(const unsigned*)(h2b + (size_t)s1 * CLASSES + 2 * lane);
            g2 = *(const unsigned*)(h2b + (size_t)s2 * CLASSES + 2 * lane);
            g3 = *(const unsigned*)(h2b + (size_t)s3 * CLASSES + 2 * lane);
        }
        float w0 = __expf(lrelu(es0 + ed));
        float w1 = __expf(lrelu(es1 + ed));
        float w2 = __expf(lrelu(es2 + ed));
        float w3 = __expf(lrelu(es3 + ed));
        denom += (w0 + w1) + (w2 + w3);
        acc0 += w0 * __uint_as_float(g0 << 16) + w1 * __uint_as_float(g1 << 16)
              + w2 * __uint_as_float(g2 << 16) + w3 * __uint_as_float(g3 << 16);
        acc1 += w0 * __uint_as_float(g0 & 0xffff0000u) + w1 * __uint_as_float(g1 & 0xffff0000u)
              + w2 * __uint_as_float(g2 & 0xffff0000u) + w3 * __uint_as_float(g3 & 0xffff0000u);
    }
    for (; i < cnt; ++i) {
        int s0 = csr[start + i];
        float w0 = __expf(lrelu(e_src[s0] + ed));
        unsigned g0 = act ? *(const unsigned*)(h2b + (size_t)s0 * CLASSES + 2 * lane) : 0;
        denom += w0;
        acc0 += w0 * __uint_as_float(g0 << 16);
        acc1 += w0 * __uint_as_float(g0 & 0xffff0000u);
    }
    if (act) {
        float inv = 1.f / (denom + 1e-16f);
        out[(size_t)d * CLASSES + 2 * lane]     = acc0 * inv + b2[2 * lane];
        out[(size_t)d * CLASSES + 2 * lane + 1] = acc1 * inv + b2[2 * lane + 1];
    }
}

extern "C" void kernel_launch(void* const* d_in, const int* in_sizes, int n_in,
                              void* d_out, int out_size, void* d_ws, size_t ws_size,
                              hipStream_t stream) {
    const float* x      = (const float*)d_in[0];
    const int*   ei     = (const int*)d_in[1];
    const float* W1     = (const float*)d_in[2];
    const float* a_src1 = (const float*)d_in[3];
    const float* a_dst1 = (const float*)d_in[4];
    const float* b1     = (const float*)d_in[5];
    const float* W2     = (const float*)d_in[6];
    const float* a_src2 = (const float*)d_in[7];
    const float* a_dst2 = (const float*)d_in[8];
    const float* b2     = (const float*)d_in[9];
    float* out = (float*)d_out;

    char* ws = (char*)d_ws;
    size_t off = 0;
    auto alloc = [&](size_t bytes) { char* p = ws + off; off += (bytes + 255) & ~(size_t)255; return p; };
    unsigned short* h1b = (unsigned short*)alloc((size_t)NN * C1 * 2);
    unsigned short* h2b = (unsigned short*)alloc((size_t)NN * CLASSES * 2);
    float* hmid   = (float*)alloc((size_t)NN * C1 * 4);
    float* e_src1 = (float*)alloc((size_t)NN * HEADS * 4);
    float* e_dst1 = (float*)alloc((size_t)NN * HEADS * 4);
    float* e_src2 = (float*)alloc((size_t)NN * 4);
    float* e_dst2 = (float*)alloc((size_t)NN * 4);
    int*   deg    = (int*)alloc((size_t)NN * 4);
    int*   rowptr = (int*)alloc((size_t)NN * 4);
    int*   cursor = (int*)alloc((size_t)NN * 4);
    unsigned short* csr = (unsigned short*)alloc((size_t)ET * 2);
    int*   bsum   = (int*)alloc(256 * 4);

    hipMemsetAsync(deg, 0, (size_t)NN * 4, stream);

    gemm1_kernel<<<(NN + 31) / 32, 256, 0, stream>>>(x, W1, h1b);
    elogit1_kernel<<<(NN * HEADS + 255) / 256, 256, 0, stream>>>(h1b, a_src1, a_dst1, e_src1, e_dst1);

    count_kernel<<<(EE / 4 + 255) / 256, 256, 0, stream>>>(ei, deg);
    const int nchunks = (NN + 1023) / 1024;  // 49
    scan1_kernel<<<nchunks, 256, 0, stream>>>(deg, rowptr, bsum);
    scan2_kernel<<<1, 64, 0, stream>>>(bsum, nchunks);
    scan3_kernel<<<(NN + 255) / 256, 256, 0, stream>>>(rowptr, bsum, cursor, csr, deg);
    fill_kernel<<<(EE / 4 + 255) / 256, 256, 0, stream>>>(ei, cursor, csr);

    agg1_kernel<<<NN / 4, 256, 0, stream>>>(h1b, e_src1, e_dst1, rowptr, deg, csr, b1, hmid);

    gemm2_kernel<<<(NN + 63) / 64, 256, 0, stream>>>(hmid, W2, h2b);
    elogit2_kernel<<<(NN + 255) / 256, 256, 0, stream>>>(h2b, a_src2, a_dst2, e_src2, e_dst2);

    agg2_kernel<<<NN / 4, 256, 0, stream>>>(h2b, e_src2, e_dst2, rowptr, deg, csr, b2, out);
}

// Round 8
// 296.520 us; speedup vs baseline: 1.0673x; 1.0198x over previous
//
#include <hip/hip_runtime.h>
#include <math.h>

#define NN 50000
#define EE 800000
#define ET (EE + NN)      // edges + self loops
#define F_IN 128
#define HEADS 8
#define HID 16
#define C1 (HEADS * HID)  // 128
#define CLASSES 40
#define NEG_SLOPE 0.2f

typedef __attribute__((ext_vector_type(8))) short bf16x8;
typedef __attribute__((ext_vector_type(4))) float f32x4;

__device__ __forceinline__ unsigned short f2bf(float f) {
    unsigned u = __float_as_uint(f);
    unsigned r = (u + 0x7fffu + ((u >> 16) & 1u)) >> 16;  // round-to-nearest-even
    return (unsigned short)r;
}
__device__ __forceinline__ float lrelu(float a) {
    return (a > 0.f) ? a : NEG_SLOPE * a;
}
__device__ __forceinline__ float bflo(unsigned u) { return __uint_as_float(u << 16); }
__device__ __forceinline__ float bfhi(unsigned u) { return __uint_as_float(u & 0xffff0000u); }

// ---------------- GEMM1 (MFMA bf16): h1b = bf16(x @ W1) ----------------
__global__ void gemm1_kernel(const float* __restrict__ x, const float* __restrict__ W1,
                             unsigned short* __restrict__ h1b) {
    const int tid = threadIdx.x;
    const int w = tid >> 6, lane = tid & 63;
    const int q = lane >> 4, c = lane & 15;

    bf16x8 bfrag[2][4];
    #pragma unroll
    for (int nt = 0; nt < 2; ++nt) {
        const int col = w * 32 + nt * 16 + c;
        #pragma unroll
        for (int kc = 0; kc < 4; ++kc) {
            const int k0 = kc * 32 + q * 8;
            bf16x8 bb;
            #pragma unroll
            for (int j = 0; j < 8; ++j)
                bb[j] = (short)f2bf(W1[(size_t)(k0 + j) * C1 + col]);
            bfrag[nt][kc] = bb;
        }
    }

    #pragma unroll
    for (int mt = 0; mt < 2; ++mt) {
        const int m0 = (blockIdx.x * 2 + mt) * 16;
        if (m0 >= NN) break;
        int row = m0 + c;
        if (row > NN - 1) row = NN - 1;
        bf16x8 afrag[4];
        #pragma unroll
        for (int kc = 0; kc < 4; ++kc) {
            const float* xp = x + (size_t)row * F_IN + kc * 32 + q * 8;
            float4 p0 = *(const float4*)xp;
            float4 p1 = *(const float4*)(xp + 4);
            bf16x8 aa;
            aa[0] = (short)f2bf(p0.x); aa[1] = (short)f2bf(p0.y);
            aa[2] = (short)f2bf(p0.z); aa[3] = (short)f2bf(p0.w);
            aa[4] = (short)f2bf(p1.x); aa[5] = (short)f2bf(p1.y);
            aa[6] = (short)f2bf(p1.z); aa[7] = (short)f2bf(p1.w);
            afrag[kc] = aa;
        }
        f32x4 acc0 = {0.f, 0.f, 0.f, 0.f};
        f32x4 acc1 = {0.f, 0.f, 0.f, 0.f};
        #pragma unroll
        for (int kc = 0; kc < 4; ++kc) {
            acc0 = __builtin_amdgcn_mfma_f32_16x16x32_bf16(afrag[kc], bfrag[0][kc], acc0, 0, 0, 0);
            acc1 = __builtin_amdgcn_mfma_f32_16x16x32_bf16(afrag[kc], bfrag[1][kc], acc1, 0, 0, 0);
        }
        #pragma unroll
        for (int r = 0; r < 4; ++r) {
            const int ro = m0 + q * 4 + r;
            if (ro < NN) {
                h1b[(size_t)ro * C1 + w * 32 + c]      = f2bf(acc0[r]);
                h1b[(size_t)ro * C1 + w * 32 + 16 + c] = f2bf(acc1[r]);
            }
        }
    }
}

// ---------------- elogit1 ----------------
__global__ void elogit1_kernel(const unsigned short* __restrict__ h1b,
                               const float* __restrict__ a_src, const float* __restrict__ a_dst,
                               float* __restrict__ e_src, float* __restrict__ e_dst) {
    int t = blockIdx.x * blockDim.x + threadIdx.x;
    if (t >= NN * HEADS) return;
    int n = t >> 3, hd = t & 7;
    const uint4* hp = (const uint4*)(h1b + (size_t)n * C1 + hd * HID);
    uint4 g0 = hp[0], g1 = hp[1];
    const float* as = a_src + hd * HID;
    const float* ad = a_dst + hd * HID;
    unsigned gs[8] = {g0.x, g0.y, g0.z, g0.w, g1.x, g1.y, g1.z, g1.w};
    float ss = 0.f, sd = 0.f;
    #pragma unroll
    for (int j = 0; j < 8; ++j) {
        float lo = bflo(gs[j]);
        float hi = bfhi(gs[j]);
        ss += lo * as[2 * j] + hi * as[2 * j + 1];
        sd += lo * ad[2 * j] + hi * ad[2 * j + 1];
    }
    e_src[t] = ss;
    e_dst[t] = sd;
}

// ---------------- CSR build (real edges only; self-loops handled in scan3) ----------------
__global__ void count_kernel(const int* __restrict__ ei, int* __restrict__ deg) {
    int base = (blockIdx.x * blockDim.x + threadIdx.x) * 4;
    if (base >= EE) return;
    int4 d4 = *(const int4*)(ei + EE + base);
    atomicAdd(&deg[d4.x], 1);
    atomicAdd(&deg[d4.y], 1);
    atomicAdd(&deg[d4.z], 1);
    atomicAdd(&deg[d4.w], 1);
}

// exclusive scan over (deg[i] + 1)  [+1 = self-loop]
__global__ void scan1_kernel(const int* __restrict__ deg, int* __restrict__ rowptr,
                             int* __restrict__ bsum) {
    __shared__ int sh[256];
    const int tid = threadIdx.x;
    const int base = blockIdx.x * 1024 + tid * 4;
    int v[4], s[4];
    #pragma unroll
    for (int j = 0; j < 4; ++j) v[j] = (base + j < NN) ? (deg[base + j] + 1) : 0;
    s[0] = v[0]; s[1] = s[0] + v[1]; s[2] = s[1] + v[2]; s[3] = s[2] + v[3];
    int T = s[3];
    sh[tid] = T;
    __syncthreads();
    for (int off = 1; off < 256; off <<= 1) {
        int xv = (tid >= off) ? sh[tid - off] : 0;
        __syncthreads();
        sh[tid] += xv;
        __syncthreads();
    }
    int excl = sh[tid] - T;
    #pragma unroll
    for (int j = 0; j < 4; ++j)
        if (base + j < NN) rowptr[base + j] = excl + s[j] - v[j];
    if (tid == 255) bsum[blockIdx.x] = sh[255];
}

__global__ void scan2_kernel(int* __restrict__ bsum, int nchunks) {
    __shared__ int sh[64];
    const int tid = threadIdx.x;
    int v = (tid < nchunks) ? bsum[tid] : 0;
    sh[tid] = v;
    __syncthreads();
    for (int off = 1; off < 64; off <<= 1) {
        int xv = (tid >= off) ? sh[tid - off] : 0;
        __syncthreads();
        sh[tid] += xv;
        __syncthreads();
    }
    if (tid < nchunks) bsum[tid] = sh[tid] - v;  // exclusive
}

// finalize rowptr; self-loop at slot rowptr[i]; cursor starts past it; deg -> total cnt
__global__ void scan3_kernel(int* __restrict__ rowptr, const int* __restrict__ bsum,
                             int* __restrict__ cursor, unsigned short* __restrict__ csr,
                             int* __restrict__ deg) {
    int i = blockIdx.x * blockDim.x + threadIdx.x;
    if (i >= NN) return;
    int rp = rowptr[i] + bsum[i >> 10];
    rowptr[i] = rp;
    cursor[i] = rp + 1;
    csr[rp] = (unsigned short)i;  // self-loop first
    deg[i] += 1;                  // total incoming count incl. self-loop
}

// scatter real edges: 4 per thread, int4 loads, ushort payloads (L2-merged stores)
__global__ void fill_kernel(const int* __restrict__ ei, int* __restrict__ cursor,
                            unsigned short* __restrict__ csr) {
    int base = (blockIdx.x * blockDim.x + threadIdx.x) * 4;
    if (base >= EE) return;
    int4 s4 = *(const int4*)(ei + base);
    int4 d4 = *(const int4*)(ei + EE + base);
    int p0 = atomicAdd(&cursor[d4.x], 1);
    int p1 = atomicAdd(&cursor[d4.y], 1);
    int p2 = atomicAdd(&cursor[d4.z], 1);
    int p3 = atomicAdd(&cursor[d4.w], 1);
    csr[p0] = (unsigned short)s4.x;
    csr[p1] = (unsigned short)s4.y;
    csr[p2] = (unsigned short)s4.z;
    csr[p3] = (unsigned short)s4.w;
}

// ---------------- layer-1 aggregation ----------------
// block = 256 = 4 waves; wave per dst node. Wave = 4 edge-groups x 16 lanes.
// Lane l (0..15) owns channels 8l..8l+7 (one dwordx4 per gather); head = l>>1.
// Group g processes edges i = g, g+4, g+8, ... (2x unrolled, stride 8).
// Final cross-group combine: shfl_xor butterflies over lanes 16,32.
__global__ void agg1_kernel(const unsigned short* __restrict__ h1b,
                            const float* __restrict__ e_src, const float* __restrict__ e_dst,
                            const int* __restrict__ rowptr, const int* __restrict__ deg,
                            const unsigned short* __restrict__ csr,
                            const float* __restrict__ b1, float* __restrict__ hmid) {
    const int d = blockIdx.x * 4 + (threadIdx.x >> 6);
    const int lane = threadIdx.x & 63;
    const int g = lane >> 4;       // edge-group 0..3
    const int l = lane & 15;       // channel-lane: channels 8l..8l+7
    const int hd = l >> 1;
    const float ed = e_dst[(size_t)d * HEADS + hd];
    const int start = rowptr[d];
    const int cnt = deg[d];

    float denom = 0.f;
    float acc[8] = {0.f, 0.f, 0.f, 0.f, 0.f, 0.f, 0.f, 0.f};

    for (int i = g; i < cnt; i += 8) {
        const int i1 = i + 4;
        const bool v1 = i1 < cnt;
        const int j1 = v1 ? i1 : i;
        int s0 = csr[start + i];
        int s1 = csr[start + j1];
        float es0 = e_src[(size_t)s0 * HEADS + hd];
        float es1 = e_src[(size_t)s1 * HEADS + hd];
        uint4 g0 = *(const uint4*)(h1b + (size_t)s0 * C1 + 8 * l);
        uint4 g1 = *(const uint4*)(h1b + (size_t)s1 * C1 + 8 * l);
        float w0 = __expf(lrelu(es0 + ed));
        float w1 = v1 ? __expf(lrelu(es1 + ed)) : 0.f;
        denom += w0 + w1;
        acc[0] += w0 * bflo(g0.x) + w1 * bflo(g1.x);
        acc[1] += w0 * bfhi(g0.x) + w1 * bfhi(g1.x);
        acc[2] += w0 * bflo(g0.y) + w1 * bflo(g1.y);
        acc[3] += w0 * bfhi(g0.y) + w1 * bfhi(g1.y);
        acc[4] += w0 * bflo(g0.z) + w1 * bflo(g1.z);
        acc[5] += w0 * bfhi(g0.z) + w1 * bfhi(g1.z);
        acc[6] += w0 * bflo(g0.w) + w1 * bflo(g1.w);
        acc[7] += w0 * bfhi(g0.w) + w1 * bfhi(g1.w);
    }
    // combine the 4 edge-groups (lanes l, l+16, l+32, l+48)
    denom += __shfl_xor(denom, 16);
    denom += __shfl_xor(denom, 32);
    #pragma unroll
    for (int k = 0; k < 8; ++k) {
        acc[k] += __shfl_xor(acc[k], 16);
        acc[k] += __shfl_xor(acc[k], 32);
    }
    if (g == 0) {
        const float inv = 1.f / (denom + 1e-16f);
        float4 oA, oB;
        float o;
        o = acc[0] * inv + b1[8 * l + 0]; oA.x = (o > 0.f) ? o : expm1f(o);
        o = acc[1] * inv + b1[8 * l + 1]; oA.y = (o > 0.f) ? o : expm1f(o);
        o = acc[2] * inv + b1[8 * l + 2]; oA.z = (o > 0.f) ? o : expm1f(o);
        o = acc[3] * inv + b1[8 * l + 3]; oA.w = (o > 0.f) ? o : expm1f(o);
        o = acc[4] * inv + b1[8 * l + 4]; oB.x = (o > 0.f) ? o : expm1f(o);
        o = acc[5] * inv + b1[8 * l + 5]; oB.y = (o > 0.f) ? o : expm1f(o);
        o = acc[6] * inv + b1[8 * l + 6]; oB.z = (o > 0.f) ? o : expm1f(o);
        o = acc[7] * inv + b1[8 * l + 7]; oB.w = (o > 0.f) ? o : expm1f(o);
        float* op = hmid + (size_t)d * C1 + 8 * l;
        *(float4*)op = oA;
        *(float4*)(op + 4) = oB;
    }
}

// ---------------- GEMM2 (MFMA bf16): h2b = bf16(hmid @ W2) ----------------
__global__ void gemm2_kernel(const float* __restrict__ hmid, const float* __restrict__ W2,
                             unsigned short* __restrict__ h2b) {
    const int tid = threadIdx.x;
    const int w = tid >> 6, lane = tid & 63;
    const int q = lane >> 4, c = lane & 15;

    bf16x8 bfrag[3][4];
    #pragma unroll
    for (int nt = 0; nt < 3; ++nt) {
        const int col = nt * 16 + c;
        const bool cv = col < CLASSES;
        #pragma unroll
        for (int kc = 0; kc < 4; ++kc) {
            const int k0 = kc * 32 + q * 8;
            bf16x8 bb;
            #pragma unroll
            for (int j = 0; j < 8; ++j)
                bb[j] = cv ? (short)f2bf(W2[(size_t)(k0 + j) * CLASSES + col]) : (short)0;
            bfrag[nt][kc] = bb;
        }
    }

    const int m0 = (blockIdx.x * 4 + w) * 16;
    if (m0 >= NN) return;
    int row = m0 + c;
    if (row > NN - 1) row = NN - 1;
    bf16x8 afrag[4];
    #pragma unroll
    for (int kc = 0; kc < 4; ++kc) {
        const float* xp = hmid + (size_t)row * F_IN + kc * 32 + q * 8;
        float4 p0 = *(const float4*)xp;
        float4 p1 = *(const float4*)(xp + 4);
        bf16x8 aa;
        aa[0] = (short)f2bf(p0.x); aa[1] = (short)f2bf(p0.y);
        aa[2] = (short)f2bf(p0.z); aa[3] = (short)f2bf(p0.w);
        aa[4] = (short)f2bf(p1.x); aa[5] = (short)f2bf(p1.y);
        aa[6] = (short)f2bf(p1.z); aa[7] = (short)f2bf(p1.w);
        afrag[kc] = aa;
    }
    f32x4 acc[3] = {{0.f,0.f,0.f,0.f},{0.f,0.f,0.f,0.f},{0.f,0.f,0.f,0.f}};
    #pragma unroll
    for (int kc = 0; kc < 4; ++kc) {
        acc[0] = __builtin_amdgcn_mfma_f32_16x16x32_bf16(afrag[kc], bfrag[0][kc], acc[0], 0, 0, 0);
        acc[1] = __builtin_amdgcn_mfma_f32_16x16x32_bf16(afrag[kc], bfrag[1][kc], acc[1], 0, 0, 0);
        acc[2] = __builtin_amdgcn_mfma_f32_16x16x32_bf16(afrag[kc], bfrag[2][kc], acc[2], 0, 0, 0);
    }
    #pragma unroll
    for (int nt = 0; nt < 3; ++nt) {
        const int col = nt * 16 + c;
        if (col >= CLASSES) continue;
        #pragma unroll
        for (int r = 0; r < 4; ++r) {
            const int ro = m0 + q * 4 + r;
            if (ro < NN) h2b[(size_t)ro * CLASSES + col] = f2bf(acc[nt][r]);
        }
    }
}

// ---------------- elogit2 ----------------
__global__ void elogit2_kernel(const unsigned short* __restrict__ h2b,
                               const float* __restrict__ a_src, const float* __restrict__ a_dst,
                               float* __restrict__ e_src, float* __restrict__ e_dst) {
    int n = blockIdx.x * blockDim.x + threadIdx.x;
    if (n >= NN) return;
    const unsigned* hp = (const unsigned*)(h2b + (size_t)n * CLASSES);
    float ss = 0.f, sd = 0.f;
    #pragma unroll
    for (int j = 0; j < CLASSES / 2; ++j) {
        unsigned g = hp[j];
        float lo = bflo(g);
        float hi = bfhi(g);
        ss += lo * a_src[2 * j] + hi * a_src[2 * j + 1];
        sd += lo * a_dst[2 * j] + hi * a_dst[2 * j + 1];
    }
    e_src[n] = ss;
    e_dst[n] = sd;
}

// ---------------- layer-2 aggregation -> output ----------------
// block = 256 = 4 waves; wave per dst node. Wave = 3 edge-groups x 20 lanes (60 active).
// Lane = eg*20 + c; lane c owns channels 2c,2c+1. Group eg processes edges i=eg, eg+3, ...
__global__ void agg2_kernel(const unsigned short* __restrict__ h2b,
                            const float* __restrict__ e_src, const float* __restrict__ e_dst,
                            const int* __restrict__ rowptr, const int* __restrict__ deg,
                            const unsigned short* __restrict__ csr,
                            const float* __restrict__ b2, float* __restrict__ out) {
    const int d = blockIdx.x * 4 + (threadIdx.x >> 6);
    const int lane = threadIdx.x & 63;
    const int eg = lane / 20;      // 0..2 active, 3 = idle lanes 60..63
    const int c  = lane % 20;
    const bool act = lane < 60;
    const float ed = e_dst[d];
    const int start = rowptr[d];
    const int cnt = deg[d];

    float denom = 0.f, acc0 = 0.f, acc1 = 0.f;
    for (int i = act ? eg : cnt; i < cnt; i += 6) {
        const int i1 = i + 3;
        const bool v1 = i1 < cnt;
        const int j1 = v1 ? i1 : i;
        int s0 = csr[start + i];
        int s1 = csr[start + j1];
        float es0 = e_src[s0], es1 = e_src[s1];
        unsigned g0 = *(const unsigned*)(h2b + (size_t)s0 * CLASSES + 2 * c);
        unsigned g1 = *(const unsigned*)(h2b + (size_t)s1 * CLASSES + 2 * c);
        float w0 = __expf(lrelu(es0 + ed));
        float w1 = v1 ? __expf(lrelu(es1 + ed)) : 0.f;
        denom += w0 + w1;
        acc0 += w0 * bflo(g0) + w1 * bflo(g1);
        acc1 += w0 * bfhi(g0) + w1 * bfhi(g1);
    }
    // combine 3 edge-groups: lanes c, c+20, c+40
    float dA = __shfl(denom, c + 20), dB = __shfl(denom, c + 40);
    float aA = __shfl(acc0,  c + 20), aB = __shfl(acc0,  c + 40);
    float bA = __shfl(acc1,  c + 20), bB = __shfl(acc1,  c + 40);
    if (lane < 20) {
        denom += dA + dB;
        acc0  += aA + aB;
        acc1  += bA + bB;
        const float inv = 1.f / (denom + 1e-16f);
        float2 o;
        o.x = acc0 * inv + b2[2 * c];
        o.y = acc1 * inv + b2[2 * c + 1];
        *(float2*)(out + (size_t)d * CLASSES + 2 * c) = o;
    }
}

extern "C" void kernel_launch(void* const* d_in, const int* in_sizes, int n_in,
                              void* d_out, int out_size, void* d_ws, size_t ws_size,
                              hipStream_t stream) {
    const float* x      = (const float*)d_in[0];
    const int*   ei     = (const int*)d_in[1];
    const float* W1     = (const float*)d_in[2];
    const float* a_src1 = (const float*)d_in[3];
    const float* a_dst1 = (const float*)d_in[4];
    const float* b1     = (const float*)d_in[5];
    const float* W2     = (const float*)d_in[6];
    const float* a_src2 = (const float*)d_in[7];
    const float* a_dst2 = (const float*)d_in[8];
    const float* b2     = (const float*)d_in[9];
    float* out = (float*)d_out;

    char* ws = (char*)d_ws;
    size_t off = 0;
    auto alloc = [&](size_t bytes) { char* p = ws + off; off += (bytes + 255) & ~(size_t)255; return p; };
    unsigned short* h1b = (unsigned short*)alloc((size_t)NN * C1 * 2);
    unsigned short* h2b = (unsigned short*)alloc((size_t)NN * CLASSES * 2);
    float* hmid   = (float*)alloc((size_t)NN * C1 * 4);
    float* e_src1 = (float*)alloc((size_t)NN * HEADS * 4);
    float* e_dst1 = (float*)alloc((size_t)NN * HEADS * 4);
    float* e_src2 = (float*)alloc((size_t)NN * 4);
    float* e_dst2 = (float*)alloc((size_t)NN * 4);
    int*   deg    = (int*)alloc((size_t)NN * 4);
    int*   rowptr = (int*)alloc((size_t)NN * 4);
    int*   cursor = (int*)alloc((size_t)NN * 4);
    unsigned short* csr = (unsigned short*)alloc((size_t)ET * 2);
    int*   bsum   = (int*)alloc(256 * 4);

    hipMemsetAsync(deg, 0, (size_t)NN * 4, stream);

    gemm1_kernel<<<(NN + 31) / 32, 256, 0, stream>>>(x, W1, h1b);
    elogit1_kernel<<<(NN * HEADS + 255) / 256, 256, 0, stream>>>(h1b, a_src1, a_dst1, e_src1, e_dst1);

    count_kernel<<<(EE / 4 + 255) / 256, 256, 0, stream>>>(ei, deg);
    const int nchunks = (NN + 1023) / 1024;  // 49
    scan1_kernel<<<nchunks, 256, 0, stream>>>(deg, rowptr, bsum);
    scan2_kernel<<<1, 64, 0, stream>>>(bsum, nchunks);
    scan3_kernel<<<(NN + 255) / 256, 256, 0, stream>>>(rowptr, bsum, cursor, csr, deg);
    fill_kernel<<<(EE / 4 + 255) / 256, 256, 0, stream>>>(ei, cursor, csr);

    agg1_kernel<<<NN / 4, 256, 0, stream>>>(h1b, e_src1, e_dst1, rowptr, deg, csr, b1, hmid);

    gemm2_kernel<<<(NN + 63) / 64, 256, 0, stream>>>(hmid, W2, h2b);
    elogit2_kernel<<<(NN + 255) / 256, 256, 0, stream>>>(h2b, a_src2, a_dst2, e_src2, e_dst2);

    agg2_kernel<<<NN / 4, 256, 0, stream>>>(h2b, e_src2, e_dst2, rowptr, deg, csr, b2, out);
}